// Round 4
// baseline (127.075 us; speedup 1.0000x reference)
//
#include <hip/hip_runtime.h>

// TensorTrainEmbedding, exact-dedup v2 (worklist + fat entries).
// out[b] = start_core[h0] . (cores[h1] . end_core[h2]); core slice = 4 KiB.
// ~36.8% of h1 draws are duplicates -> fetch each distinct core slice ONCE.
// R3 lesson: dedup must not lengthen the dependent-load chain. Here:
//   build:    hs -> counts[h1]++, table[h1][slot] = {b,h0,h2}   (one pass)
//   compact:  non-empty bins -> worklist[i] = h1 | cnt<<20      (one pass)
//   main:     worklist(L2) -> (core || entries) -> (start || end) -> out
// Per-b arithmetic identical to R1 regardless of bin/slot order -> deterministic.

#define CAP 8           // slots per bin; Poisson(1) overflow handled separately
#define WPB 4           // waves per block
#define T_STRIDE 20     // LDS t-exchange stride: <=2-way bank alias (free)
#define HRANGE_C 131072
#define MAIN_BLOCKS 8192
#define OVF_BLOCKS 32

// ws layout (bytes)
#define WS_COUNTS_OFF 0                       // HRANGE u32 = 512 KiB
#define WS_CTRS_OFF   (HRANGE_C * 4)          // [0]=nwork, [1]=novf
#define WS_WORK_OFF   (1u << 20)              // HRANGE u32 = 512 KiB
#define WS_OVF_OFF    ((1u << 20) + (HRANGE_C * 4))
#define WS_TABLE_OFF  (2u << 20)              // HRANGE*CAP uint4 = 16 MiB
#define WS_NEEDED     ((2u << 20) + (size_t)HRANGE_C * CAP * 16)

#define WAVE_LDS_FENCE() do { \
    asm volatile("s_waitcnt lgkmcnt(0)" ::: "memory"); \
    __builtin_amdgcn_sched_barrier(0); \
} while (0)

__global__ __launch_bounds__(256) void build_kernel(
    const int* __restrict__ hs, unsigned* __restrict__ counts,
    uint4* __restrict__ table, unsigned* __restrict__ ctrs,
    unsigned* __restrict__ ovf, int B)
{
    int b = blockIdx.x * 256 + threadIdx.x;
    if (b >= B) return;
    unsigned h0 = (unsigned)hs[3 * b + 0];
    unsigned h1 = (unsigned)hs[3 * b + 1];
    unsigned h2 = (unsigned)hs[3 * b + 2];
    unsigned slot = atomicAdd(&counts[h1], 1u);
    if (slot < CAP) {
        table[h1 * CAP + slot] = make_uint4((unsigned)b, h0, h2, 0u);
    } else {
        unsigned o = atomicAdd(&ctrs[1], 1u);
        ovf[o] = (unsigned)b;
    }
}

__global__ __launch_bounds__(256) void compact_kernel(
    const unsigned* __restrict__ counts, unsigned* __restrict__ ctrs,
    unsigned* __restrict__ worklist)
{
    int h = blockIdx.x * 256 + threadIdx.x;   // grid covers HRANGE exactly
    unsigned c = counts[h];
    if (c > 0) {
        unsigned cc = c > CAP ? (unsigned)CAP : c;
        unsigned s = atomicAdd(&ctrs[0], 1u);  // compiler wave-coalesces
        worklist[s] = (unsigned)h | (cc << 20);
    }
}

__global__ __launch_bounds__(256) void tt_main_kernel(
    const float* __restrict__ start_core,
    const float* __restrict__ end_core,
    const float* __restrict__ cores,
    const unsigned* __restrict__ ctrs,
    const unsigned* __restrict__ worklist,
    const uint4* __restrict__ table,
    float* __restrict__ out)
{
    __shared__ __align__(16) float lds_t[WPB][16 * T_STRIDE];

    const int tid  = threadIdx.x;
    const int wave = tid >> 6;
    const int lane = tid & 63;

    const int n = __builtin_amdgcn_readfirstlane((int)ctrs[0]);
    const int stride = MAIN_BLOCKS * WPB;

    const int d = lane >> 4;
    const int s = lane & 15;
    float* tw = &lds_t[wave][(d * 4) * T_STRIDE + s];
    const float* tr = &lds_t[wave][(lane & 15) * T_STRIDE];

    for (int i = blockIdx.x * WPB + wave; i < n; i += stride) {
        const unsigned w = (unsigned)__builtin_amdgcn_readfirstlane(
                               (int)worklist[i]);
        const int h1  = (int)(w & 0xFFFFFu);
        const int cnt = (int)(w >> 20);

        // core slice (4 KiB) fetched once; issues concurrently with entry load
        const float* crp = cores + ((size_t)h1 << 10) + lane * 16;
        float c[16];
        *(float4*)(c + 0)  = *(const float4*)(crp + 0);
        *(float4*)(c + 4)  = *(const float4*)(crp + 4);
        *(float4*)(c + 8)  = *(const float4*)(crp + 8);
        *(float4*)(c + 12) = *(const float4*)(crp + 12);

        const uint4* ep = table + (size_t)h1 * CAP;

        for (int j = 0; j < cnt; ++j) {
            const uint4 e = ep[j];   // wave-uniform address -> scalar load
            const int b  = __builtin_amdgcn_readfirstlane((int)e.x);
            const int h0 = __builtin_amdgcn_readfirstlane((int)e.y);
            const int h2 = __builtin_amdgcn_readfirstlane((int)e.z);

            const float* stp = start_core + ((size_t)h0 << 6) + ((lane >> 4) << 4);
            float st[16];
            *(float4*)(st + 0)  = *(const float4*)(stp + 0);
            *(float4*)(st + 4)  = *(const float4*)(stp + 4);
            *(float4*)(st + 8)  = *(const float4*)(stp + 8);
            *(float4*)(st + 12) = *(const float4*)(stp + 12);

            const float* v0p = end_core + ((size_t)h2 << 6);
            #pragma unroll
            for (int e4 = 0; e4 < 4; ++e4) {
                const float* ve = v0p + e4 * 16;
                float a = c[0] * ve[0];
                #pragma unroll
                for (int r = 1; r < 16; ++r)
                    a = fmaf(c[r], ve[r], a);
                tw[e4 * T_STRIDE] = a;
            }

            WAVE_LDS_FENCE();

            float tt[16];
            *(float4*)(tt + 0)  = *(const float4*)(tr + 0);
            *(float4*)(tt + 4)  = *(const float4*)(tr + 4);
            *(float4*)(tt + 8)  = *(const float4*)(tr + 8);
            *(float4*)(tt + 12) = *(const float4*)(tr + 12);

            float a = st[0] * tt[0];
            #pragma unroll
            for (int k = 1; k < 16; ++k)
                a = fmaf(st[k], tt[k], a);

            out[((size_t)b << 6) + lane] = a;

            WAVE_LDS_FENCE();   // WAR vs next iteration's t writes
        }
    }
}

// overflow cleanup: elements whose bin exceeded CAP (expected ~0)
__global__ __launch_bounds__(256) void tt_ovf_kernel(
    const int* __restrict__ hs,
    const float* __restrict__ start_core,
    const float* __restrict__ end_core,
    const float* __restrict__ cores,
    const unsigned* __restrict__ ctrs,
    const unsigned* __restrict__ ovf,
    float* __restrict__ out)
{
    __shared__ __align__(16) float lds_t[WPB][16 * T_STRIDE];
    const int tid  = threadIdx.x;
    const int wave = tid >> 6;
    const int lane = tid & 63;

    const int nv = __builtin_amdgcn_readfirstlane((int)ctrs[1]);

    for (int k = blockIdx.x * WPB + wave; k < nv; k += OVF_BLOCKS * WPB) {
        const int b  = __builtin_amdgcn_readfirstlane((int)ovf[k]);
        const int h0 = __builtin_amdgcn_readfirstlane(hs[3 * b + 0]);
        const int h1 = __builtin_amdgcn_readfirstlane(hs[3 * b + 1]);
        const int h2 = __builtin_amdgcn_readfirstlane(hs[3 * b + 2]);

        const float* crp = cores + ((size_t)h1 << 10) + lane * 16;
        float c[16];
        *(float4*)(c + 0)  = *(const float4*)(crp + 0);
        *(float4*)(c + 4)  = *(const float4*)(crp + 4);
        *(float4*)(c + 8)  = *(const float4*)(crp + 8);
        *(float4*)(c + 12) = *(const float4*)(crp + 12);

        const float* stp = start_core + ((size_t)h0 << 6) + ((lane >> 4) << 4);
        float st[16];
        *(float4*)(st + 0)  = *(const float4*)(stp + 0);
        *(float4*)(st + 4)  = *(const float4*)(stp + 4);
        *(float4*)(st + 8)  = *(const float4*)(stp + 8);
        *(float4*)(st + 12) = *(const float4*)(stp + 12);

        const float* v0p = end_core + ((size_t)h2 << 6);
        const int d = lane >> 4;
        const int s = lane & 15;
        #pragma unroll
        for (int e4 = 0; e4 < 4; ++e4) {
            const float* ve = v0p + e4 * 16;
            float a = c[0] * ve[0];
            #pragma unroll
            for (int r = 1; r < 16; ++r)
                a = fmaf(c[r], ve[r], a);
            lds_t[wave][(d * 4 + e4) * T_STRIDE + s] = a;
        }

        WAVE_LDS_FENCE();

        const float* tp = &lds_t[wave][(lane & 15) * T_STRIDE];
        float tt[16];
        *(float4*)(tt + 0)  = *(const float4*)(tp + 0);
        *(float4*)(tt + 4)  = *(const float4*)(tp + 4);
        *(float4*)(tt + 8)  = *(const float4*)(tp + 8);
        *(float4*)(tt + 12) = *(const float4*)(tp + 12);

        float a = st[0] * tt[0];
        #pragma unroll
        for (int kk = 1; kk < 16; ++kk)
            a = fmaf(st[kk], tt[kk], a);
        out[((size_t)b << 6) + lane] = a;

        WAVE_LDS_FENCE();
    }
}

// plain fallback (R1 kernel) for unexpected shapes / small ws
__global__ __launch_bounds__(256) void tt_plain_kernel(
    const int* __restrict__ hs,
    const float* __restrict__ start_core,
    const float* __restrict__ end_core,
    const float* __restrict__ cores,
    float* __restrict__ out,
    int B)
{
    __shared__ __align__(16) float lds_t[WPB][16 * T_STRIDE];
    const int tid  = threadIdx.x;
    const int wave = tid >> 6;
    const int lane = tid & 63;

    int b = blockIdx.x * WPB + wave;
    b = __builtin_amdgcn_readfirstlane(b);
    if (b >= B) return;

    const int h0 = __builtin_amdgcn_readfirstlane(hs[3 * b + 0]);
    const int h1 = __builtin_amdgcn_readfirstlane(hs[3 * b + 1]);
    const int h2 = __builtin_amdgcn_readfirstlane(hs[3 * b + 2]);

    const float* crp = cores + ((size_t)h1 << 10) + lane * 16;
    float c[16];
    *(float4*)(c + 0)  = *(const float4*)(crp + 0);
    *(float4*)(c + 4)  = *(const float4*)(crp + 4);
    *(float4*)(c + 8)  = *(const float4*)(crp + 8);
    *(float4*)(c + 12) = *(const float4*)(crp + 12);

    const float* stp = start_core + ((size_t)h0 << 6) + ((lane >> 4) << 4);
    float st[16];
    *(float4*)(st + 0)  = *(const float4*)(stp + 0);
    *(float4*)(st + 4)  = *(const float4*)(stp + 4);
    *(float4*)(st + 8)  = *(const float4*)(stp + 8);
    *(float4*)(st + 12) = *(const float4*)(stp + 12);

    const float* v0p = end_core + ((size_t)h2 << 6);
    const int d = lane >> 4;
    const int s = lane & 15;
    #pragma unroll
    for (int e4 = 0; e4 < 4; ++e4) {
        const float* ve = v0p + e4 * 16;
        float a = c[0] * ve[0];
        #pragma unroll
        for (int r = 1; r < 16; ++r)
            a = fmaf(c[r], ve[r], a);
        lds_t[wave][(d * 4 + e4) * T_STRIDE + s] = a;
    }

    WAVE_LDS_FENCE();

    const float* tp = &lds_t[wave][(lane & 15) * T_STRIDE];
    float tt[16];
    *(float4*)(tt + 0)  = *(const float4*)(tp + 0);
    *(float4*)(tt + 4)  = *(const float4*)(tp + 4);
    *(float4*)(tt + 8)  = *(const float4*)(tp + 8);
    *(float4*)(tt + 12) = *(const float4*)(tp + 12);

    float a = st[0] * tt[0];
    #pragma unroll
    for (int kk = 1; kk < 16; ++kk)
        a = fmaf(st[kk], tt[kk], a);
    out[((size_t)b << 6) + lane] = a;
}

extern "C" void kernel_launch(void* const* d_in, const int* in_sizes, int n_in,
                              void* d_out, int out_size, void* d_ws, size_t ws_size,
                              hipStream_t stream) {
    const int*   hs         = (const int*)d_in[0];
    const float* start_core = (const float*)d_in[1];
    const float* end_core   = (const float*)d_in[2];
    const float* cores      = (const float*)d_in[3];
    float* out = (float*)d_out;

    const int B = in_sizes[0] / 3;   // hs is (B, 3)

    const bool dedup = (B == HRANGE_C) && (ws_size >= WS_NEEDED);

    if (dedup) {
        unsigned* counts   = (unsigned*)((char*)d_ws + WS_COUNTS_OFF);
        unsigned* ctrs     = (unsigned*)((char*)d_ws + WS_CTRS_OFF);
        unsigned* worklist = (unsigned*)((char*)d_ws + WS_WORK_OFF);
        unsigned* ovf      = (unsigned*)((char*)d_ws + WS_OVF_OFF);
        uint4*    table    = (uint4*)((char*)d_ws + WS_TABLE_OFF);

        // zero counts + both counters (contiguous)
        hipMemsetAsync(d_ws, 0, HRANGE_C * 4 + 16, stream);
        hipLaunchKernelGGL(build_kernel, dim3((B + 255) / 256), dim3(256), 0,
                           stream, hs, counts, table, ctrs, ovf, B);
        hipLaunchKernelGGL(compact_kernel, dim3(HRANGE_C / 256), dim3(256), 0,
                           stream, counts, ctrs, worklist);
        hipLaunchKernelGGL(tt_main_kernel, dim3(MAIN_BLOCKS), dim3(256), 0,
                           stream, start_core, end_core, cores, ctrs, worklist,
                           table, out);
        hipLaunchKernelGGL(tt_ovf_kernel, dim3(OVF_BLOCKS), dim3(256), 0,
                           stream, hs, start_core, end_core, cores, ctrs, ovf,
                           out);
    } else {
        hipLaunchKernelGGL(tt_plain_kernel, dim3((B + WPB - 1) / WPB),
                           dim3(256), 0, stream,
                           hs, start_core, end_core, cores, out, B);
    }
}